// Round 1
// 423.335 us; speedup vs baseline: 1.0437x; 1.0437x over previous
//
#include <hip/hip_runtime.h>
#include <hip/hip_bf16.h>
#include <hip/hip_fp16.h>

// Problem constants (match reference)
#define NN 100000
#define EE 1600000
#define INF_DIM 128
#define NHEAD 4
#define HDIM 32
#define NEG_SLOPE 0.2f

typedef __attribute__((ext_vector_type(8))) short short8;
typedef __attribute__((ext_vector_type(4))) float floatx4;

__device__ __forceinline__ unsigned short f2bf(float x) {
  union { float f; unsigned int u; } c;
  c.f = x;
  const unsigned int r = c.u + 0x7fffu + ((c.u >> 16) & 1u);  // RNE
  return (unsigned short)(r >> 16);
}
__device__ __forceinline__ float bf2f(unsigned short u) {
  union { unsigned int u; float f; } c;
  c.u = ((unsigned int)u) << 16;
  return c.f;
}
// unpack packed pair of bf16 (from one u32) to two floats
__device__ __forceinline__ void bf2x(unsigned int u, float& lo, float& hi) {
  union { unsigned int u; float f; } a, b;
  a.u = u << 16;
  b.u = u & 0xffff0000u;
  lo = a.f;
  hi = b.f;
}
__device__ __forceinline__ unsigned int packh2(float a, float b) {
  const __half ha = __float2half(a), hb = __float2half(b);
  const unsigned short ua = *(const unsigned short*)&ha;
  const unsigned short ub = *(const unsigned short*)&hb;
  return (unsigned int)ua | ((unsigned int)ub << 16);
}
// select fp16 weight for this lane's head out of packed {y=h01, z=h23}
__device__ __forceinline__ float pickw(const int4 e, const int head) {
  const unsigned int d = (head & 2) ? (unsigned int)e.z : (unsigned int)e.y;
  const unsigned short us =
      (head & 1) ? (unsigned short)(d >> 16) : (unsigned short)(d & 0xffffu);
  const __half h = *(const __half*)&us;
  return __half2float(h);
}
// fma 8 bf16 features (one uint4) into acc[8] with scalar weight c
__device__ __forceinline__ void accum8(const uint4 g, const float c,
                                       float* acc) {
  float lo, hi;
  bf2x(g.x, lo, hi);
  acc[0] = fmaf(c, lo, acc[0]);
  acc[1] = fmaf(c, hi, acc[1]);
  bf2x(g.y, lo, hi);
  acc[2] = fmaf(c, lo, acc[2]);
  acc[3] = fmaf(c, hi, acc[3]);
  bf2x(g.z, lo, hi);
  acc[4] = fmaf(c, lo, acc[4]);
  acc[5] = fmaf(c, hi, acc[5]);
  bf2x(g.w, lo, hi);
  acc[6] = fmaf(c, lo, acc[6]);
  acc[7] = fmaf(c, hi, acc[7]);
}

// ---------------------------------------------------------------------------
// MFMA GEMM: C[M,128] = A[M,128] @ W[128,128]^T (+bias), W row-major [o][k].
// A input: fp32 (Af) or bf16 (Ab). Output: bf16 (Cb) or fp32+bias (Cf).
// Block = 64 rows x 128 cols, 4 waves; K=128 staged once to LDS (bf16).
// ---------------------------------------------------------------------------
#define LDA 136

__global__ __launch_bounds__(256) void gemm_mfma(
    const float* __restrict__ Af, const unsigned short* __restrict__ Ab,
    const float* __restrict__ W, const float* __restrict__ bias,
    unsigned short* __restrict__ Cb, float* __restrict__ Cf, int M) {
  __shared__ unsigned short sA[64 * LDA];   // [m][k]
  __shared__ unsigned short sW[128 * LDA];  // [o][k] == B^T
  const int tid = threadIdx.x;
  const int m0 = blockIdx.x * 64;

  {
    const int r = tid >> 1;
    const int c0 = (tid & 1) * 64;
#pragma unroll
    for (int j = 0; j < 16; ++j) {
      const float4 v = *(const float4*)&W[r * 128 + c0 + j * 4];
      ushort4 u;
      u.x = f2bf(v.x);
      u.y = f2bf(v.y);
      u.z = f2bf(v.z);
      u.w = f2bf(v.w);
      *(ushort4*)&sW[r * LDA + c0 + j * 4] = u;
    }
  }
  {
    const int r = tid >> 2;
    const int gm = m0 + r;
    const int c0 = (tid & 3) * 32;
    if (gm < M) {
      if (Af) {
#pragma unroll
        for (int j = 0; j < 8; ++j) {
          const float4 v = *(const float4*)&Af[(size_t)gm * 128 + c0 + j * 4];
          ushort4 u;
          u.x = f2bf(v.x);
          u.y = f2bf(v.y);
          u.z = f2bf(v.z);
          u.w = f2bf(v.w);
          *(ushort4*)&sA[r * LDA + c0 + j * 4] = u;
        }
      } else {
#pragma unroll
        for (int j = 0; j < 4; ++j) {
          const uint4 v = *(const uint4*)&Ab[(size_t)gm * 128 + c0 + j * 8];
          *(uint4*)&sA[r * LDA + c0 + j * 8] = v;
        }
      }
    } else {
#pragma unroll
      for (int j = 0; j < 4; ++j) {
        uint4 z;
        z.x = z.y = z.z = z.w = 0u;
        *(uint4*)&sA[r * LDA + c0 + j * 8] = z;
      }
    }
  }
  __syncthreads();

  const int wv = tid >> 6;
  const int lane = tid & 63;
  const int l16 = lane & 15;
  const int quad = lane >> 4;

  floatx4 acc[8];
#pragma unroll
  for (int i = 0; i < 8; ++i) acc[i] = (floatx4){0.f, 0.f, 0.f, 0.f};

  const unsigned short* aRow = &sA[(wv * 16 + l16) * LDA + quad * 8];
#pragma unroll
  for (int kc = 0; kc < 4; ++kc) {
    const short8 afrag = *(const short8*)(aRow + kc * 32);
#pragma unroll
    for (int nt = 0; nt < 8; ++nt) {
      const short8 bfrag =
          *(const short8*)&sW[(nt * 16 + l16) * LDA + kc * 32 + quad * 8];
      acc[nt] =
          __builtin_amdgcn_mfma_f32_16x16x32_bf16(afrag, bfrag, acc[nt], 0, 0, 0);
    }
  }

  const int mrow = m0 + wv * 16 + quad * 4;
#pragma unroll
  for (int nt = 0; nt < 8; ++nt) {
    const int col = nt * 16 + l16;
    const float bv = Cf ? bias[col] : 0.f;
#pragma unroll
    for (int r = 0; r < 4; ++r) {
      const int gm = mrow + r;
      if (gm < M) {
        const float v = acc[nt][r];
        if (Cb)
          Cb[(size_t)gm * 128 + col] = f2bf(v);
        else
          Cf[(size_t)gm * 128 + col] = v + bv;
      }
    }
  }
}

// ---------------------------------------------------------------------------
// a_s[n,h] = dot(hb[n,h,:], att_src[h,:]); a_d likewise. One thread per (n,h).
// ---------------------------------------------------------------------------
__global__ void attn_dots(const unsigned short* __restrict__ hb,
                          const float* __restrict__ att_src,
                          const float* __restrict__ att_dst,
                          float* __restrict__ a_s, float* __restrict__ a_d) {
  const int idx = blockIdx.x * blockDim.x + threadIdx.x;  // n*4 + head
  if (idx >= NN * NHEAD) return;
  const int hd = idx & 3;
  const uint4* hp = (const uint4*)(hb + (size_t)idx * HDIM);
  const float4* as = (const float4*)(att_src + hd * HDIM);
  const float4* ad = (const float4*)(att_dst + hd * HDIM);
  float s = 0.f, d = 0.f;
#pragma unroll
  for (int q = 0; q < 4; ++q) {
    const uint4 u = hp[q];
    float v[8];
    bf2x(u.x, v[0], v[1]);
    bf2x(u.y, v[2], v[3]);
    bf2x(u.z, v[4], v[5]);
    bf2x(u.w, v[6], v[7]);
    const float4 a0 = as[q * 2], a1 = as[q * 2 + 1];
    const float4 b0 = ad[q * 2], b1 = ad[q * 2 + 1];
    s += v[0] * a0.x + v[1] * a0.y + v[2] * a0.z + v[3] * a0.w;
    s += v[4] * a1.x + v[5] * a1.y + v[6] * a1.z + v[7] * a1.w;
    d += v[0] * b0.x + v[1] * b0.y + v[2] * b0.z + v[3] * b0.w;
    d += v[4] * b1.x + v[5] * b1.y + v[6] * b1.z + v[7] * b1.w;
  }
  a_s[idx] = s;
  a_d[idx] = d;
}

// ---------------------------------------------------------------------------
// CSR build: histogram of dst, segment allocation via wave-scan + one atomic
// per wave, scatter (fused with per-edge softmax-weight precompute; emits
// 16 B records {src, fp16 w01, fp16 w23, 0}).
// ---------------------------------------------------------------------------
__global__ void hist_kernel(const int* __restrict__ dst, int* __restrict__ deg) {
  const int i = blockIdx.x * blockDim.x + threadIdx.x;
  if (i < EE) atomicAdd(&deg[dst[i]], 1);
}

__global__ __launch_bounds__(256) void alloc_kernel(const int* __restrict__ deg,
                                                    int* __restrict__ rowptr,
                                                    int* __restrict__ cur,
                                                    int* __restrict__ counter) {
  const int i = blockIdx.x * blockDim.x + threadIdx.x;
  const int lane = threadIdx.x & 63;
  const int d = (i < NN) ? deg[i] : 0;
  int s = d;
#pragma unroll
  for (int off = 1; off < 64; off <<= 1) {
    const int v = __shfl_up(s, off, 64);
    if (lane >= off) s += v;
  }
  const int total = __shfl(s, 63, 64);
  int base = 0;
  if (lane == 63) base = atomicAdd(counter, total);
  base = __shfl(base, 63, 64);
  const int p = base + s - d;
  if (i < NN) {
    rowptr[i] = p;
    cur[i] = p;
  }
}

__global__ void scatter_kernel(const int* __restrict__ src,
                               const int* __restrict__ dst,
                               const float* __restrict__ a_s,
                               const float* __restrict__ a_d,
                               int* __restrict__ cur, int4* __restrict__ ebuf) {
  const int i = blockIdx.x * blockDim.x + threadIdx.x;
  if (i >= EE) return;
  const int s = src[i];
  const int d = dst[i];
  const int p = atomicAdd(&cur[d], 1);
  const float4 as = *(const float4*)&a_s[s * 4];
  const float4 ad = *(const float4*)&a_d[d * 4];
  float4 l;
  l.x = as.x + ad.x;
  l.y = as.y + ad.y;
  l.z = as.z + ad.z;
  l.w = as.w + ad.w;
  l.x = l.x > 0.f ? l.x : NEG_SLOPE * l.x;
  l.y = l.y > 0.f ? l.y : NEG_SLOPE * l.y;
  l.z = l.z > 0.f ? l.z : NEG_SLOPE * l.z;
  l.w = l.w > 0.f ? l.w : NEG_SLOPE * l.w;
  int4 e;
  e.x = s;
  e.y = (int)packh2(__expf(l.x), __expf(l.y));
  e.z = (int)packh2(__expf(l.z), __expf(l.w));
  e.w = 0;
  ebuf[p] = e;
}

// ---------------------------------------------------------------------------
// Aggregate v2: one wave per destination node, quarter-wave per edge.
// Lane layout: q = lane>>4 (edge slot), f = lane&15 (feature group).
// Lane owns features [8f, 8f+8) -> one uint4 (16 B) of the bf16 feature row;
// its head is f>>2 (head-aligned: 8f..8f+7 all inside head f>>2).
// Per loop iteration the wave processes 4 edges: one uint4 record load/lane
// (4 records = 64 B, one cache line per quarter-group) + one uint4 gather.
// Edge records are software-pipelined (prefetch i+4 before consuming gather).
// Per-head softmax denominator + features reduce across quarters via
// shfl_xor(16/32); quarter 0 packs bf16 and stores.
// ---------------------------------------------------------------------------
__global__ __launch_bounds__(256) void aggregate_kernel(
    const uint4* __restrict__ hbd4, const float* __restrict__ a_s,
    const float* __restrict__ a_d, const float* __restrict__ bias_gat,
    const int* __restrict__ rowptr, const int* __restrict__ deg,
    const int4* __restrict__ ebuf, uint4* __restrict__ obd4) {
  const int wave = (blockIdx.x * blockDim.x + threadIdx.x) >> 6;
  if (wave >= NN) return;
  const int lane = threadIdx.x & 63;
  const int q = lane >> 4;
  const int f = lane & 15;
  const int head = f >> 2;
  const int n = wave;

  float acc[8];
  float ds;
  {  // self loop (only quarter 0 contributes; others start at zero)
    const float l0 = a_s[n * 4 + head] + a_d[n * 4 + head];
    const float l = fmaxf(l0, NEG_SLOPE * l0);
    float cs = __expf(l);
    if (q != 0) cs = 0.f;
    const uint4 g = hbd4[(size_t)n * 16 + f];
    float lo, hi;
    bf2x(g.x, lo, hi);
    acc[0] = cs * lo;
    acc[1] = cs * hi;
    bf2x(g.y, lo, hi);
    acc[2] = cs * lo;
    acc[3] = cs * hi;
    bf2x(g.z, lo, hi);
    acc[4] = cs * lo;
    acc[5] = cs * hi;
    bf2x(g.w, lo, hi);
    acc[6] = cs * lo;
    acc[7] = cs * hi;
    ds = cs;
  }

  const int beg = rowptr[n];
  const int end = beg + deg[n];
  if (beg < end) {
    int idx = beg + q;
    bool valid = idx < end;
    int4 e = ebuf[valid ? idx : end - 1];
    for (int i = beg; i < end; i += 4) {
      // gather current 4 edges' features (one uint4/lane)
      const uint4 g = hbd4[(size_t)e.x * 16 + f];
      // prefetch next records while the gather is in flight
      const int nidx = i + 4 + q;
      const bool nvalid = nidx < end;
      const int4 en = ebuf[nvalid ? nidx : end - 1];
      // weight for this lane's head (zero on masked tail slots)
      float c = pickw(e, head);
      if (!valid) c = 0.f;
      accum8(g, c, acc);
      ds += c;
      e = en;
      valid = nvalid;
    }
  }

  // reduce across the 4 quarters (lanes l, l^16, l^32, l^48 share f)
#pragma unroll
  for (int j = 0; j < 8; ++j) {
    acc[j] += __shfl_xor(acc[j], 16);
    acc[j] += __shfl_xor(acc[j], 32);
  }
  ds += __shfl_xor(ds, 16);
  ds += __shfl_xor(ds, 32);

  if (q == 0) {
    const float inv = 1.0f / ds;
    const float4 b0 = *(const float4*)&bias_gat[f * 8];
    const float4 b1 = *(const float4*)&bias_gat[f * 8 + 4];
    float v0 = acc[0] * inv + b0.x;
    float v1 = acc[1] * inv + b0.y;
    float v2 = acc[2] * inv + b0.z;
    float v3 = acc[3] * inv + b0.w;
    float v4 = acc[4] * inv + b1.x;
    float v5 = acc[5] * inv + b1.y;
    float v6 = acc[6] * inv + b1.z;
    float v7 = acc[7] * inv + b1.w;
    v0 = v0 > 0.f ? v0 : 0.f;
    v1 = v1 > 0.f ? v1 : 0.f;
    v2 = v2 > 0.f ? v2 : 0.f;
    v3 = v3 > 0.f ? v3 : 0.f;
    v4 = v4 > 0.f ? v4 : 0.f;
    v5 = v5 > 0.f ? v5 : 0.f;
    v6 = v6 > 0.f ? v6 : 0.f;
    v7 = v7 > 0.f ? v7 : 0.f;
    uint4 r;
    r.x = (unsigned int)f2bf(v0) | ((unsigned int)f2bf(v1) << 16);
    r.y = (unsigned int)f2bf(v2) | ((unsigned int)f2bf(v3) << 16);
    r.z = (unsigned int)f2bf(v4) | ((unsigned int)f2bf(v5) << 16);
    r.w = (unsigned int)f2bf(v6) | ((unsigned int)f2bf(v7) << 16);
    obd4[(size_t)n * 16 + f] = r;
  }
}

// ---------------------------------------------------------------------------
extern "C" void kernel_launch(void* const* d_in, const int* in_sizes, int n_in,
                              void* d_out, int out_size, void* d_ws,
                              size_t ws_size, hipStream_t stream) {
  const float* x = (const float*)d_in[0];
  const int* ei = (const int*)d_in[1];  // [2,E]: row0=src, row1=dst
  const float* W_gat = (const float*)d_in[2];
  const float* att_src = (const float*)d_in[3];
  const float* att_dst = (const float*)d_in[4];
  const float* bias_gat = (const float*)d_in[5];
  const float* W_lin = (const float*)d_in[6];
  const float* b_lin = (const float*)d_in[7];
  float* out = (float*)d_out;

  // workspace carve-up (16B aligned)
  char* ws = (char*)d_ws;
  size_t off = 0;
  unsigned short* hb = (unsigned short*)(ws + off);
  off += (size_t)NN * 128 * 2;  // 25.6 MB
  unsigned short* ob = (unsigned short*)(ws + off);
  off += (size_t)NN * 128 * 2;  // 25.6 MB
  float* a_s = (float*)(ws + off); off += (size_t)NN * 4 * 4;
  float* a_d = (float*)(ws + off); off += (size_t)NN * 4 * 4;
  int* deg = (int*)(ws + off); off += (size_t)NN * 4;
  int* rowptr = (int*)(ws + off); off += (size_t)(NN + 4) * 4;
  int* cur = (int*)(ws + off); off += (size_t)NN * 4;
  int* counter = (int*)(ws + off); off += 16;
  int4* ebuf = (int4*)(ws + off); off += (size_t)EE * 16;  // 25.6 MB

  const int* src = ei;
  const int* dst = ei + EE;

  // 1) hb = bf16(x @ W_gat^T)  [MFMA]
  gemm_mfma<<<(NN + 63) / 64, 256, 0, stream>>>(x, nullptr, W_gat, nullptr, hb,
                                                nullptr, NN);
  // 2) attention dots from bf16 features
  attn_dots<<<(NN * NHEAD + 255) / 256, 256, 0, stream>>>(hb, att_src, att_dst,
                                                          a_s, a_d);
  // 3) CSR by destination + fused edge-record precompute
  hipMemsetAsync(deg, 0, (size_t)NN * 4, stream);
  hipMemsetAsync(counter, 0, 16, stream);
  hist_kernel<<<(EE + 255) / 256, 256, 0, stream>>>(dst, deg);
  alloc_kernel<<<(NN + 255) / 256, 256, 0, stream>>>(deg, rowptr, cur, counter);
  scatter_kernel<<<(EE + 255) / 256, 256, 0, stream>>>(src, dst, a_s, a_d, cur,
                                                       ebuf);
  // 4) softmax-weighted aggregation (+bias, relu) -> bf16
  aggregate_kernel<<<(NN + 3) / 4, 256, 0, stream>>>(
      (const uint4*)hb, a_s, a_d, bias_gat, rowptr, deg, ebuf,
      (uint4*)ob);
  // 5) out = ob @ W_lin^T + b_lin  [MFMA]
  gemm_mfma<<<(NN + 63) / 64, 256, 0, stream>>>(nullptr, ob, W_lin, b_lin,
                                                nullptr, out, NN);
}